// Round 10
// baseline (122.362 us; speedup 1.0000x reference)
//
#include <hip/hip_runtime.h>

// x (N,S,C,V) = (8,2048,4,64) fp32; embedding (C,K,V) = (4,512,64) fp32.
#define NROW 16384   // N*S
#define CCH  4
#define KCB  512
#define VDIM 64

typedef __attribute__((ext_vector_type(8))) short  short8;   // 8 x bf16
typedef __attribute__((ext_vector_type(4))) float  floatx4;  // MFMA acc

// round-to-nearest-even fp32 -> bf16 bits; rem = v - bf16(v)
__device__ inline unsigned short bf16h(float v, float* rem) {
    unsigned u = __float_as_uint(v);
    unsigned r = u + 0x7FFFu + ((u >> 16) & 1u);
    unsigned short h = (unsigned short)(r >> 16);
    *rem = v - __uint_as_float((unsigned)h << 16);
    return h;
}
__device__ inline unsigned short bf16r(float v) {   // RNE round only
    unsigned u = __float_as_uint(v);
    return (unsigned short)((u + 0x7FFFu + ((u >> 16) & 1u)) >> 16);
}

// Block = 1024 thr (16 waves) = 1 block/CU; grid = (NROW/256, CCH) = 256.
// __launch_bounds__(1024, 4): 4 waves/EU = 1 block/CU -> VGPR cap 128.
// (R9 identical geometry at default bounds got capped to 64 VGPRs for a
// phantom 2nd block -> ~150 MB scratch spill; FETCH 87/WRITE 114 MB.)
// Codebook staged ONCE per CU (bf16-hi 64 KB + e2 2 KB). Wave (z,wb):
// 32 rows (2 row-groups) x half the codebook (codes [z*256, +256)).
// Cross-z argmin merged via 4 KB LDS table (z ascending, strict < =>
// reference first-min). Numerics: x hi/lo bf16, e bf16, e2 exact fp32;
// argmin on d' = e2 - 2*xe (x2 row-constant drops out); exact fp32 epilogue.
__global__ __launch_bounds__(1024, 4)
void vq_fused(const float* __restrict__ x, const float* __restrict__ emb,
              float* __restrict__ out) {
    extern __shared__ char smem[];
    unsigned short* eh  = (unsigned short*)smem;          // 64 KB codebook bf16
    float*          e2t = (float*)(smem + 65536);         // 2 KB  e2 transposed
    float*          sdm = (float*)(smem + 67584);         // 2 KB  [z][wb][32] d
    int*            skm = (int*)  (smem + 69632);         // 2 KB  [z][wb][32] k

    const int tid  = threadIdx.x;
    const int lane = tid & 63;
    const int m    = lane & 15;
    const int quad = lane >> 4;
    const int wave = tid >> 6;        // 0..15
    const int z    = wave >> 3;       // codebook half
    const int wb   = wave & 7;        // row block within the 256-row tile
    const int c    = blockIdx.y;
    const int rowblk = blockIdx.x * 256 + wb * 32;

    const float* embc = emb + (size_t)c * (KCB * VDIM);

    // ---- staging: thread owns (code = tid>>1, v-half = tid&1) ----
    {
        const int code = tid >> 1, vh = tid & 1;
        const float4* ef = (const float4*)embc + code * 16 + vh * 8;
        float4 f[8];
#pragma unroll
        for (int j = 0; j < 8; ++j) f[j] = ef[j];
        float s = 0.f;
#pragma unroll
        for (int j = 0; j < 8; ++j) {
            s = fmaf(f[j].x, f[j].x, s); s = fmaf(f[j].y, f[j].y, s);
            s = fmaf(f[j].z, f[j].z, s); s = fmaf(f[j].w, f[j].w, s);
        }
        s += __shfl_xor(s, 1, 64);                 // pair-sum: full e2
        if (vh == 0) e2t[(code & 15) * 32 + (code >> 4)] = s;
#pragma unroll
        for (int p = 0; p < 4; ++p) {              // 4 k-octets per v-half
            const int koct = vh * 4 + p;
            const float4 a = f[2 * p], b = f[2 * p + 1];
            short8 hv;
            hv[0] = (short)bf16r(a.x); hv[1] = (short)bf16r(a.y);
            hv[2] = (short)bf16r(a.z); hv[3] = (short)bf16r(a.w);
            hv[4] = (short)bf16r(b.x); hv[5] = (short)bf16r(b.y);
            hv[6] = (short)bf16r(b.z); hv[7] = (short)bf16r(b.w);
            *(short8*)&eh[(koct * 512 + (code ^ koct)) * 8] = hv;  // XOR swizzle
        }
    }

    // ---- A fragments: 2 row-groups x 2 k-halves, x hi/lo ----
    short8 ah[2][2], al[2][2];
#pragma unroll
    for (int g = 0; g < 2; ++g) {
        const int row = rowblk + g * 16 + m;
        const float4* xr = (const float4*)(x + ((size_t)row * CCH + c) * VDIM);
#pragma unroll
        for (int h = 0; h < 2; ++h) {              // k = h*32 + quad*8 + j
            const float4 f0 = xr[h * 8 + quad * 2];
            const float4 f1 = xr[h * 8 + quad * 2 + 1];
            const float fv[8] = {f0.x, f0.y, f0.z, f0.w, f1.x, f1.y, f1.z, f1.w};
            short8 hh, ll;
#pragma unroll
            for (int j = 0; j < 8; ++j) {
                float r, d;
                hh[j] = (short)bf16h(fv[j], &r);
                ll[j] = (short)bf16h(r, &d);
            }
            ah[g][h] = hh; al[g][h] = ll;
        }
    }

    __syncthreads();

    // e2 preload: lane m's codes are z*256 + t*16 + m, t = 0..15
    float e2r[16];
    {
        const float4* ep = (const float4*)&e2t[m * 32 + z * 16];
#pragma unroll
        for (int i = 0; i < 4; ++i) {
            const float4 v = ep[i];
            e2r[4*i] = v.x; e2r[4*i+1] = v.y; e2r[4*i+2] = v.z; e2r[4*i+3] = v.w;
        }
    }

    float bd[2][4]; int bkk[2][4];
#pragma unroll
    for (int g = 0; g < 2; ++g)
#pragma unroll
        for (int j = 0; j < 4; ++j) { bd[g][j] = 3.4e38f; bkk[g][j] = 0; }

    const int mq0 = m ^ quad, mq1 = m ^ (quad + 4);
    short8 c0 = *(const short8*)&eh[( quad      * 512 + z * 256 + mq0) * 8];
    short8 c1 = *(const short8*)&eh[((quad + 4) * 512 + z * 256 + mq1) * 8];

#pragma unroll
    for (int t = 0; t < 16; ++t) {                 // 16 tiles = this z-half
        short8 n0 = c0, n1 = c1;
        if (t < 15) {                              // prefetch next tile
            const int nb = z * 256 + (t + 1) * 16;
            n0 = *(const short8*)&eh[( quad      * 512 + nb + mq0) * 8];
            n1 = *(const short8*)&eh[((quad + 4) * 512 + nb + mq1) * 8];
        }
        // 2 independent 4-deep chains (one per row-group), B shared
        floatx4 a0 = {0.f,0.f,0.f,0.f}, a1 = {0.f,0.f,0.f,0.f};
        a0 = __builtin_amdgcn_mfma_f32_16x16x32_bf16(ah[0][0], c0, a0, 0, 0, 0);
        a1 = __builtin_amdgcn_mfma_f32_16x16x32_bf16(ah[1][0], c0, a1, 0, 0, 0);
        a0 = __builtin_amdgcn_mfma_f32_16x16x32_bf16(al[0][0], c0, a0, 0, 0, 0);
        a1 = __builtin_amdgcn_mfma_f32_16x16x32_bf16(al[1][0], c0, a1, 0, 0, 0);
        a0 = __builtin_amdgcn_mfma_f32_16x16x32_bf16(ah[0][1], c1, a0, 0, 0, 0);
        a1 = __builtin_amdgcn_mfma_f32_16x16x32_bf16(ah[1][1], c1, a1, 0, 0, 0);
        a0 = __builtin_amdgcn_mfma_f32_16x16x32_bf16(al[0][1], c1, a0, 0, 0, 0);
        a1 = __builtin_amdgcn_mfma_f32_16x16x32_bf16(al[1][1], c1, a1, 0, 0, 0);

        const int code = z * 256 + t * 16 + m;
#pragma unroll
        for (int j = 0; j < 4; ++j) {
            const float d0 = fmaf(-2.0f, a0[j], e2r[t]);
            const float d1 = fmaf(-2.0f, a1[j], e2r[t]);
            if (d0 < bd[0][j]) { bd[0][j] = d0; bkk[0][j] = code; }
            if (d1 < bd[1][j]) { bd[1][j] = d1; bkk[1][j] = code; }
        }
        c0 = n0; c1 = n1;
    }

    // within-quad (16-lane) argmin; tie -> lower code (first-occurrence)
#pragma unroll
    for (int g = 0; g < 2; ++g)
#pragma unroll
    for (int j = 0; j < 4; ++j) {
        float d = bd[g][j]; int k = bkk[g][j];
#pragma unroll
        for (int mask = 1; mask < 16; mask <<= 1) {
            const float od = __shfl_xor(d, mask, 64);
            const int   ok = __shfl_xor(k, mask, 64);
            if (od < d || (od == d && ok < k)) { d = od; k = ok; }
        }
        bd[g][j] = d; bkk[g][j] = k;
    }

    // publish per-half results
    if (m == 0) {
#pragma unroll
        for (int g = 0; g < 2; ++g)
#pragma unroll
        for (int j = 0; j < 4; ++j) {
            const int rl = g * 16 + quad * 4 + j;
            sdm[(z * 8 + wb) * 32 + rl] = bd[g][j];
            skm[(z * 8 + wb) * 32 + rl] = bkk[g][j];
        }
    }
    __syncthreads();

    // merge halves + epilogue: wave (z,wb) handles rows rl = z*16 + quad*4 + j
    const size_t base1 = (size_t)NROW * CCH * VDIM;
    const size_t base2 = base1 + (size_t)NROW * CCH;
#pragma unroll
    for (int j = 0; j < 4; ++j) {
        const int rl  = z * 16 + quad * 4 + j;
        const float d0 = sdm[(0 * 8 + wb) * 32 + rl];
        const float d1 = sdm[(1 * 8 + wb) * 32 + rl];
        const int   k0 = skm[(0 * 8 + wb) * 32 + rl];
        const int   k1 = skm[(1 * 8 + wb) * 32 + rl];
        const int code = (d1 < d0) ? k1 : k0;      // z0 first => first-min
        const int row  = rowblk + rl;

        const float4 t4 = ((const float4*)(x + ((size_t)row * CCH + c) * VDIM))[m];
        const float4 e4 = ((const float4*)(embc + (size_t)code * VDIM))[m];
        float4 w;
        w.x = (e4.x - t4.x) + t4.x;                // out0 = (output - x) + x
        w.y = (e4.y - t4.y) + t4.y;
        w.z = (e4.z - t4.z) + t4.z;
        w.w = (e4.w - t4.w) + t4.w;
        ((float4*)(out + ((size_t)row * CCH + c) * VDIM))[m] = w;
        float s = 0.f, dx;
        dx = t4.x - e4.x; s = fmaf(dx, dx, s);
        dx = t4.y - e4.y; s = fmaf(dx, dx, s);
        dx = t4.z - e4.z; s = fmaf(dx, dx, s);
        dx = t4.w - e4.w; s = fmaf(dx, dx, s);
        s += __shfl_xor(s, 1, 64);
        s += __shfl_xor(s, 2, 64);
        s += __shfl_xor(s, 4, 64);
        s += __shfl_xor(s, 8, 64);
        if (m == 0) {
            const size_t idx = (size_t)row * CCH + c;
            out[base1 + idx] = s;                  // out1
            out[base2 + idx] = s;                  // out2 (identical in ref)
        }
    }
}

extern "C" void kernel_launch(void* const* d_in, const int* in_sizes, int n_in,
                              void* d_out, int out_size, void* d_ws, size_t ws_size,
                              hipStream_t stream) {
    const float* x   = (const float*)d_in[0];
    const float* emb = (const float*)d_in[1];
    float* out = (float*)d_out;
    const size_t lds_bytes = 65536u + 2048u + 2048u + 2048u;   // 71680 B
    vq_fused<<<dim3(NROW / 256, CCH), dim3(1024), lds_bytes, stream>>>(x, emb, out);
}

// Round 11
// 117.466 us; speedup vs baseline: 1.0417x; 1.0417x over previous
//
#include <hip/hip_runtime.h>

// x (N,S,C,V) = (8,2048,4,64) fp32; embedding (C,K,V) = (4,512,64) fp32.
#define NROW 16384   // N*S
#define CCH  4
#define KCB  512
#define VDIM 64

typedef __attribute__((ext_vector_type(8))) short  short8;   // 8 x bf16
typedef __attribute__((ext_vector_type(4))) float  floatx4;  // MFMA acc

// round-to-nearest-even fp32 -> bf16 bits; rem = v - bf16(v)
__device__ inline unsigned short bf16h(float v, float* rem) {
    unsigned u = __float_as_uint(v);
    unsigned r = u + 0x7FFFu + ((u >> 16) & 1u);
    unsigned short h = (unsigned short)(r >> 16);
    *rem = v - __uint_as_float((unsigned)h << 16);
    return h;
}
__device__ inline unsigned short bf16r(float v) {   // RNE round only
    unsigned u = __float_as_uint(v);
    return (unsigned short)((u + 0x7FFFu + ((u >> 16) & 1u)) >> 16);
}

// Block = 1024 thr (16 waves) = 1 block/CU; grid = (NROW/256, CCH) = 256.
// amdgpu_waves_per_eu(4,4): pins the scheduler's occupancy TARGET at
// 4 waves/EU -> VGPR budget 128. (R9/R10 evidence: launch_bounds(1024,4)
// only sets the minimum; scheduler still targeted 8 waves/EU -> VGPR 64 ->
// ~150 MB scratch spill: FETCH 87/WRITE 114 MB, VALUBusy 14%.)
// Codebook staged ONCE per CU (bf16-hi 64 KB + e2 2 KB). Wave (z,wb):
// 32 rows (2 row-groups) x half the codebook (codes [z*256, +256)).
// Cross-z argmin merged via 4 KB LDS table (z ascending, strict < =>
// reference first-min). Numerics: x hi/lo bf16, e bf16, e2 exact fp32;
// argmin on d' = e2 - 2*xe (x2 row-constant drops out); exact fp32 epilogue.
__attribute__((amdgpu_waves_per_eu(4, 4)))
__global__ __launch_bounds__(1024)
void vq_fused(const float* __restrict__ x, const float* __restrict__ emb,
              float* __restrict__ out) {
    extern __shared__ char smem[];
    unsigned short* eh  = (unsigned short*)smem;          // 64 KB codebook bf16
    float*          e2t = (float*)(smem + 65536);         // 2 KB  e2 transposed
    float*          sdm = (float*)(smem + 67584);         // 2 KB  [z][wb][32] d
    int*            skm = (int*)  (smem + 69632);         // 2 KB  [z][wb][32] k

    const int tid  = threadIdx.x;
    const int lane = tid & 63;
    const int m    = lane & 15;
    const int quad = lane >> 4;
    const int wave = tid >> 6;        // 0..15
    const int z    = wave >> 3;       // codebook half
    const int wb   = wave & 7;        // row block within the 256-row tile
    const int c    = blockIdx.y;
    const int rowblk = blockIdx.x * 256 + wb * 32;

    const float* embc = emb + (size_t)c * (KCB * VDIM);

    // ---- staging: thread owns (code = tid>>1, v-half = tid&1) ----
    {
        const int code = tid >> 1, vh = tid & 1;
        const float4* ef = (const float4*)embc + code * 16 + vh * 8;
        float4 f[8];
#pragma unroll
        for (int j = 0; j < 8; ++j) f[j] = ef[j];
        float s = 0.f;
#pragma unroll
        for (int j = 0; j < 8; ++j) {
            s = fmaf(f[j].x, f[j].x, s); s = fmaf(f[j].y, f[j].y, s);
            s = fmaf(f[j].z, f[j].z, s); s = fmaf(f[j].w, f[j].w, s);
        }
        s += __shfl_xor(s, 1, 64);                 // pair-sum: full e2
        if (vh == 0) e2t[(code & 15) * 32 + (code >> 4)] = s;
#pragma unroll
        for (int p = 0; p < 4; ++p) {              // 4 k-octets per v-half
            const int koct = vh * 4 + p;
            const float4 a = f[2 * p], b = f[2 * p + 1];
            short8 hv;
            hv[0] = (short)bf16r(a.x); hv[1] = (short)bf16r(a.y);
            hv[2] = (short)bf16r(a.z); hv[3] = (short)bf16r(a.w);
            hv[4] = (short)bf16r(b.x); hv[5] = (short)bf16r(b.y);
            hv[6] = (short)bf16r(b.z); hv[7] = (short)bf16r(b.w);
            *(short8*)&eh[(koct * 512 + (code ^ koct)) * 8] = hv;  // XOR swizzle
        }
    }

    // ---- A fragments: 2 row-groups x 2 k-halves, x hi/lo ----
    short8 ah[2][2], al[2][2];
#pragma unroll
    for (int g = 0; g < 2; ++g) {
        const int row = rowblk + g * 16 + m;
        const float4* xr = (const float4*)(x + ((size_t)row * CCH + c) * VDIM);
#pragma unroll
        for (int h = 0; h < 2; ++h) {              // k = h*32 + quad*8 + j
            const float4 f0 = xr[h * 8 + quad * 2];
            const float4 f1 = xr[h * 8 + quad * 2 + 1];
            const float fv[8] = {f0.x, f0.y, f0.z, f0.w, f1.x, f1.y, f1.z, f1.w};
            short8 hh, ll;
#pragma unroll
            for (int j = 0; j < 8; ++j) {
                float r, d;
                hh[j] = (short)bf16h(fv[j], &r);
                ll[j] = (short)bf16h(r, &d);
            }
            ah[g][h] = hh; al[g][h] = ll;
        }
    }

    __syncthreads();

    // e2 preload: lane m's codes are z*256 + t*16 + m, t = 0..15
    float e2r[16];
    {
        const float4* ep = (const float4*)&e2t[m * 32 + z * 16];
#pragma unroll
        for (int i = 0; i < 4; ++i) {
            const float4 v = ep[i];
            e2r[4*i] = v.x; e2r[4*i+1] = v.y; e2r[4*i+2] = v.z; e2r[4*i+3] = v.w;
        }
    }

    float bd[2][4]; int bkk[2][4];
#pragma unroll
    for (int g = 0; g < 2; ++g)
#pragma unroll
        for (int j = 0; j < 4; ++j) { bd[g][j] = 3.4e38f; bkk[g][j] = 0; }

    const int mq0 = m ^ quad, mq1 = m ^ (quad + 4);
    short8 c0 = *(const short8*)&eh[( quad      * 512 + z * 256 + mq0) * 8];
    short8 c1 = *(const short8*)&eh[((quad + 4) * 512 + z * 256 + mq1) * 8];

#pragma unroll
    for (int t = 0; t < 16; ++t) {                 // 16 tiles = this z-half
        short8 n0 = c0, n1 = c1;
        if (t < 15) {                              // prefetch next tile
            const int nb = z * 256 + (t + 1) * 16;
            n0 = *(const short8*)&eh[( quad      * 512 + nb + mq0) * 8];
            n1 = *(const short8*)&eh[((quad + 4) * 512 + nb + mq1) * 8];
        }
        // 2 independent 4-deep chains (one per row-group), B shared
        floatx4 a0 = {0.f,0.f,0.f,0.f}, a1 = {0.f,0.f,0.f,0.f};
        a0 = __builtin_amdgcn_mfma_f32_16x16x32_bf16(ah[0][0], c0, a0, 0, 0, 0);
        a1 = __builtin_amdgcn_mfma_f32_16x16x32_bf16(ah[1][0], c0, a1, 0, 0, 0);
        a0 = __builtin_amdgcn_mfma_f32_16x16x32_bf16(al[0][0], c0, a0, 0, 0, 0);
        a1 = __builtin_amdgcn_mfma_f32_16x16x32_bf16(al[1][0], c0, a1, 0, 0, 0);
        a0 = __builtin_amdgcn_mfma_f32_16x16x32_bf16(ah[0][1], c1, a0, 0, 0, 0);
        a1 = __builtin_amdgcn_mfma_f32_16x16x32_bf16(ah[1][1], c1, a1, 0, 0, 0);
        a0 = __builtin_amdgcn_mfma_f32_16x16x32_bf16(al[0][1], c1, a0, 0, 0, 0);
        a1 = __builtin_amdgcn_mfma_f32_16x16x32_bf16(al[1][1], c1, a1, 0, 0, 0);

        const int code = z * 256 + t * 16 + m;
#pragma unroll
        for (int j = 0; j < 4; ++j) {
            const float d0 = fmaf(-2.0f, a0[j], e2r[t]);
            const float d1 = fmaf(-2.0f, a1[j], e2r[t]);
            if (d0 < bd[0][j]) { bd[0][j] = d0; bkk[0][j] = code; }
            if (d1 < bd[1][j]) { bd[1][j] = d1; bkk[1][j] = code; }
        }
        c0 = n0; c1 = n1;
    }

    // within-quad (16-lane) argmin; tie -> lower code (first-occurrence)
#pragma unroll
    for (int g = 0; g < 2; ++g)
#pragma unroll
    for (int j = 0; j < 4; ++j) {
        float d = bd[g][j]; int k = bkk[g][j];
#pragma unroll
        for (int mask = 1; mask < 16; mask <<= 1) {
            const float od = __shfl_xor(d, mask, 64);
            const int   ok = __shfl_xor(k, mask, 64);
            if (od < d || (od == d && ok < k)) { d = od; k = ok; }
        }
        bd[g][j] = d; bkk[g][j] = k;
    }

    // publish per-half results
    if (m == 0) {
#pragma unroll
        for (int g = 0; g < 2; ++g)
#pragma unroll
        for (int j = 0; j < 4; ++j) {
            const int rl = g * 16 + quad * 4 + j;
            sdm[(z * 8 + wb) * 32 + rl] = bd[g][j];
            skm[(z * 8 + wb) * 32 + rl] = bkk[g][j];
        }
    }
    __syncthreads();

    // merge halves + epilogue: wave (z,wb) handles rows rl = z*16 + quad*4 + j
    const size_t base1 = (size_t)NROW * CCH * VDIM;
    const size_t base2 = base1 + (size_t)NROW * CCH;
#pragma unroll
    for (int j = 0; j < 4; ++j) {
        const int rl  = z * 16 + quad * 4 + j;
        const float d0 = sdm[(0 * 8 + wb) * 32 + rl];
        const float d1 = sdm[(1 * 8 + wb) * 32 + rl];
        const int   k0 = skm[(0 * 8 + wb) * 32 + rl];
        const int   k1 = skm[(1 * 8 + wb) * 32 + rl];
        const int code = (d1 < d0) ? k1 : k0;      // z0 first => first-min
        const int row  = rowblk + rl;

        const float4 t4 = ((const float4*)(x + ((size_t)row * CCH + c) * VDIM))[m];
        const float4 e4 = ((const float4*)(embc + (size_t)code * VDIM))[m];
        float4 w;
        w.x = (e4.x - t4.x) + t4.x;                // out0 = (output - x) + x
        w.y = (e4.y - t4.y) + t4.y;
        w.z = (e4.z - t4.z) + t4.z;
        w.w = (e4.w - t4.w) + t4.w;
        ((float4*)(out + ((size_t)row * CCH + c) * VDIM))[m] = w;
        float s = 0.f, dx;
        dx = t4.x - e4.x; s = fmaf(dx, dx, s);
        dx = t4.y - e4.y; s = fmaf(dx, dx, s);
        dx = t4.z - e4.z; s = fmaf(dx, dx, s);
        dx = t4.w - e4.w; s = fmaf(dx, dx, s);
        s += __shfl_xor(s, 1, 64);
        s += __shfl_xor(s, 2, 64);
        s += __shfl_xor(s, 4, 64);
        s += __shfl_xor(s, 8, 64);
        if (m == 0) {
            const size_t idx = (size_t)row * CCH + c;
            out[base1 + idx] = s;                  // out1
            out[base2 + idx] = s;                  // out2 (identical in ref)
        }
    }
}

extern "C" void kernel_launch(void* const* d_in, const int* in_sizes, int n_in,
                              void* d_out, int out_size, void* d_ws, size_t ws_size,
                              hipStream_t stream) {
    const float* x   = (const float*)d_in[0];
    const float* emb = (const float*)d_in[1];
    float* out = (float*)d_out;
    const size_t lds_bytes = 65536u + 2048u + 2048u + 2048u;   // 71680 B
    vq_fused<<<dim3(NROW / 256, CCH), dim3(1024), lds_bytes, stream>>>(x, emb, out);
}

// Round 12
// 96.146 us; speedup vs baseline: 1.2727x; 1.2217x over previous
//
#include <hip/hip_runtime.h>

// x (N,S,C,V) = (8,2048,4,64) fp32; embedding (C,K,V) = (4,512,64) fp32.
#define NROW 16384   // N*S
#define CCH  4
#define KCB  512
#define VDIM 64

typedef __attribute__((ext_vector_type(8))) short  short8;   // 8 x bf16
typedef __attribute__((ext_vector_type(4))) float  floatx4;  // MFMA acc

// round-to-nearest-even fp32 -> bf16 bits; rem = v - bf16(v)
__device__ inline unsigned short bf16h(float v, float* rem) {
    unsigned u = __float_as_uint(v);
    unsigned r = u + 0x7FFFu + ((u >> 16) & 1u);
    unsigned short h = (unsigned short)(r >> 16);
    *rem = v - __uint_as_float((unsigned)h << 16);
    return h;
}
__device__ inline unsigned short bf16r(float v) {   // RNE round only
    unsigned u = __float_as_uint(v);
    return (unsigned short)((u + 0x7FFFu + ((u >> 16) & 1u)) >> 16);
}

// Block = 512 thr (8 waves) = (z in {0,1}) x (wb in {0..3}); grid =
// (NROW/64, CCH) = 1024 blocks; LDS 67 KB -> 2 blocks/CU = 16 waves/CU.
// Wave (z,wb): 16 rows x HALF the codebook (codes [z*256, +256)) -> 16
// serial tile-chains per wave instead of R8's 32 (R8 is latency-bound
// within-wave). Live set ~55 VGPRs: fits the allocator's 64-VGPR target
// honestly — R9/R10/R11's 1024-thr geometry needed ~100 and spilled
// ~100 MB scratch regardless of launch_bounds/waves_per_eu attributes.
// Cross-z argmin merged via 1 KB LDS table (z ascending, strict < =>
// reference first-min). Numerics: x hi/lo bf16, e bf16, e2 exact fp32;
// argmin on d' = e2 - 2*xe (x2 row-constant drops out); exact fp32 epilogue.
__global__ __launch_bounds__(512, 4)
void vq_fused(const float* __restrict__ x, const float* __restrict__ emb,
              float* __restrict__ out) {
    extern __shared__ char smem[];
    unsigned short* eh  = (unsigned short*)smem;          // 64 KB codebook bf16
    float*          e2s = (float*)(smem + 65536);         // 2 KB  e2 fp32
    float*          sdm = (float*)(smem + 67584);         // 512 B [z*4+wb][16]
    int*            skm = (int*)  (smem + 68096);         // 512 B

    const int tid  = threadIdx.x;
    const int lane = tid & 63;
    const int m    = lane & 15;
    const int quad = lane >> 4;
    const int wave = tid >> 6;        // 0..7
    const int z    = wave >> 2;       // codebook half
    const int wb   = wave & 3;        // row block
    const int c    = blockIdx.y;
    const int rbase = blockIdx.x * 64 + wb * 16;

    const float* embc = emb + (size_t)c * (KCB * VDIM);

    // --- stage codebook (R8 scheme): wave covers 64 codes, 16 coalesced
    //     1KB wave-reads; XOR-swizzled LDS layout; fused exact-fp32 e2 ---
    {
        const int cb = wave * 64;
        const int koct = m >> 1, half = m & 1;
#pragma unroll
        for (int j = 0; j < 16; ++j) {
            const int g = cb * 16 + j * 64 + lane;       // float4 index
            const float4 t = ((const float4*)embc)[g];
            const int code = cb + j * 4 + quad;
            ushort4 h4;
            h4.x = bf16r(t.x); h4.y = bf16r(t.y);
            h4.z = bf16r(t.z); h4.w = bf16r(t.w);
            const int off = (koct * 512 + (code ^ koct)) * 8 + half * 4;
            *(ushort4*)&eh[off] = h4;
            float s = 0.f;
            s = fmaf(t.x, t.x, s); s = fmaf(t.y, t.y, s);
            s = fmaf(t.z, t.z, s); s = fmaf(t.w, t.w, s);
            s += __shfl_xor(s, 1, 64);
            s += __shfl_xor(s, 2, 64);
            s += __shfl_xor(s, 4, 64);
            s += __shfl_xor(s, 8, 64);
            if (m == 0) e2s[code] = s;
        }
    }

    // --- A fragments: 16 rows, 2 k-halves, x hi/lo ---
    short8 ah[2], al[2];
    {
        const int row = rbase + m;
        const float4* xr = (const float4*)(x + ((size_t)row * CCH + c) * VDIM);
#pragma unroll
        for (int h = 0; h < 2; ++h) {              // k = h*32 + quad*8 + j
            const float4 f0 = xr[h * 8 + quad * 2];
            const float4 f1 = xr[h * 8 + quad * 2 + 1];
            const float fv[8] = {f0.x, f0.y, f0.z, f0.w, f1.x, f1.y, f1.z, f1.w};
            short8 hh, ll;
#pragma unroll
            for (int j = 0; j < 8; ++j) {
                float r, d;
                hh[j] = (short)bf16h(fv[j], &r);
                ll[j] = (short)bf16h(r, &d);
            }
            ah[h] = hh; al[h] = ll;
        }
    }

    __syncthreads();

    float bd[4]; int bkk[4];
#pragma unroll
    for (int j = 0; j < 4; ++j) { bd[j] = 3.4e38f; bkk[j] = 0; }

    const int mq0 = m ^ quad, mq1 = m ^ (quad + 4);
    const int kbase = z * 256;

#pragma unroll 4
    for (int t = 0; t < 16; ++t) {                 // 16 tiles = this z-half
        const int kb = kbase + t * 16;
        const int code = kb + m;
        const short8 bh0 = *(const short8*)&eh[( quad      * 512 + kb + mq0) * 8];
        const short8 bh1 = *(const short8*)&eh[((quad + 4) * 512 + kb + mq1) * 8];
        const float e2v = e2s[code];

        // 2 independent depth-2 chains: acc0 = xh.e, acc1 = xl.e
        floatx4 acc0 = {0.f,0.f,0.f,0.f}, acc1 = {0.f,0.f,0.f,0.f};
        acc0 = __builtin_amdgcn_mfma_f32_16x16x32_bf16(ah[0], bh0, acc0, 0, 0, 0);
        acc1 = __builtin_amdgcn_mfma_f32_16x16x32_bf16(al[0], bh0, acc1, 0, 0, 0);
        acc0 = __builtin_amdgcn_mfma_f32_16x16x32_bf16(ah[1], bh1, acc0, 0, 0, 0);
        acc1 = __builtin_amdgcn_mfma_f32_16x16x32_bf16(al[1], bh1, acc1, 0, 0, 0);

#pragma unroll
        for (int j = 0; j < 4; ++j) {
            const float d0 = fmaf(-2.0f, acc0[j] + acc1[j], e2v);
            if (d0 < bd[j]) { bd[j] = d0; bkk[j] = code; }  // strict < = first-min
        }
    }

    // within-quad (16-lane) argmin; tie -> lower code (first-occurrence)
#pragma unroll
    for (int j = 0; j < 4; ++j) {
        float d = bd[j]; int k = bkk[j];
#pragma unroll
        for (int mask = 1; mask < 16; mask <<= 1) {
            const float od = __shfl_xor(d, mask, 64);
            const int   ok = __shfl_xor(k, mask, 64);
            if (od < d || (od == d && ok < k)) { d = od; k = ok; }
        }
        bd[j] = d; bkk[j] = k;
    }

    // publish per-half results: lane m==0 of each quad holds rows quad*4+j
    if (m == 0) {
#pragma unroll
        for (int j = 0; j < 4; ++j) {
            sdm[(z * 4 + wb) * 16 + quad * 4 + j] = bd[j];
            skm[(z * 4 + wb) * 16 + quad * 4 + j] = bkk[j];
        }
    }
    __syncthreads();

    // merge halves + epilogue: z==0 waves handle their 16 rows
    if (z == 0) {
        const size_t base1 = (size_t)NROW * CCH * VDIM;
        const size_t base2 = base1 + (size_t)NROW * CCH;
#pragma unroll
        for (int j = 0; j < 4; ++j) {
            const int rl = quad * 4 + j;
            const float d0 = sdm[ wb      * 16 + rl];
            const float d1 = sdm[(4 + wb) * 16 + rl];
            const int   k0 = skm[ wb      * 16 + rl];
            const int   k1 = skm[(4 + wb) * 16 + rl];
            const int code = (d1 < d0) ? k1 : k0;  // z0 first => first-min
            const int row  = rbase + rl;

            const float4 t4 = ((const float4*)(x + ((size_t)row * CCH + c) * VDIM))[m];
            const float4 e4 = ((const float4*)(embc + (size_t)code * VDIM))[m];
            float4 w;
            w.x = (e4.x - t4.x) + t4.x;            // out0 = (output - x) + x
            w.y = (e4.y - t4.y) + t4.y;
            w.z = (e4.z - t4.z) + t4.z;
            w.w = (e4.w - t4.w) + t4.w;
            ((float4*)(out + ((size_t)row * CCH + c) * VDIM))[m] = w;
            float s = 0.f, dx;
            dx = t4.x - e4.x; s = fmaf(dx, dx, s);
            dx = t4.y - e4.y; s = fmaf(dx, dx, s);
            dx = t4.z - e4.z; s = fmaf(dx, dx, s);
            dx = t4.w - e4.w; s = fmaf(dx, dx, s);
            s += __shfl_xor(s, 1, 64);
            s += __shfl_xor(s, 2, 64);
            s += __shfl_xor(s, 4, 64);
            s += __shfl_xor(s, 8, 64);
            if (m == 0) {
                const size_t idx = (size_t)row * CCH + c;
                out[base1 + idx] = s;              // out1
                out[base2 + idx] = s;              // out2 (identical in ref)
            }
        }
    }
}

extern "C" void kernel_launch(void* const* d_in, const int* in_sizes, int n_in,
                              void* d_out, int out_size, void* d_ws, size_t ws_size,
                              hipStream_t stream) {
    const float* x   = (const float*)d_in[0];
    const float* emb = (const float*)d_in[1];
    float* out = (float*)d_out;
    const size_t lds_bytes = 65536u + 2048u + 512u + 512u;   // 68608 B
    vq_fused<<<dim3(NROW / 64, CCH), dim3(512), lds_bytes, stream>>>(x, emb, out);
}

// Round 13
// 90.660 us; speedup vs baseline: 1.3497x; 1.0605x over previous
//
#include <hip/hip_runtime.h>

// x (N,S,C,V) = (8,2048,4,64) fp32; embedding (C,K,V) = (4,512,64) fp32.
#define NROW 16384   // N*S
#define CCH  4
#define KCB  512
#define VDIM 64

typedef __attribute__((ext_vector_type(8))) short  short8;   // 8 x bf16
typedef __attribute__((ext_vector_type(4))) float  floatx4;  // MFMA acc

// round-to-nearest-even fp32 -> bf16 bits; rem = v - bf16(v)
__device__ inline unsigned short bf16h(float v, float* rem) {
    unsigned u = __float_as_uint(v);
    unsigned r = u + 0x7FFFu + ((u >> 16) & 1u);
    unsigned short h = (unsigned short)(r >> 16);
    *rem = v - __uint_as_float((unsigned)h << 16);
    return h;
}
__device__ inline unsigned short bf16r(float v) {   // RNE round only
    unsigned u = __float_as_uint(v);
    return (unsigned short)((u + 0x7FFFu + ((u >> 16) & 1u)) >> 16);
}

// Block = 512 thr (8 waves) = (z in {0,1}) x (wb in {0..3}); grid =
// (NROW/128, CCH) = 512 blocks -> exactly 2 co-resident blocks/CU
// (LDS 2 x 68.6 KB), 16 waves/CU. Each block: stage codebook ONCE
// (shuffle-free: thread tid owns code tid — 16 L2-hot dwordx4 reads,
// in-thread exact-fp32 e2, 8 ds_write_b128), then TWO row-tiles of 64
// rows (staging amortized 2x vs R12's 4 stagings/CU with 64 DS-shuffles
// each). Wave (z,wb): 16 rows x half the codebook (codes [z*256,+256)).
// Cross-z argmin via 1 KB LDS table (z ascending, strict < => reference
// first-min). Numerics identical to R12: x hi/lo bf16, e bf16, e2 exact
// fp32; argmin on d' = e2 - 2*xe (x2 row-constant drops out); exact fp32
// epilogue. R12 counters: VGPR 40, zero spill, 0 LDS conflicts.
__global__ __launch_bounds__(512, 4)
void vq_fused(const float* __restrict__ x, const float* __restrict__ emb,
              float* __restrict__ out) {
    extern __shared__ char smem[];
    unsigned short* eh  = (unsigned short*)smem;          // 64 KB codebook bf16
    float*          e2s = (float*)(smem + 65536);         // 2 KB  e2 fp32
    float*          sdm = (float*)(smem + 67584);         // 512 B [z*4+wb][16]
    int*            skm = (int*)  (smem + 68096);         // 512 B

    const int tid  = threadIdx.x;
    const int lane = tid & 63;
    const int m    = lane & 15;
    const int quad = lane >> 4;
    const int wave = tid >> 6;        // 0..7
    const int z    = wave >> 2;       // codebook half
    const int wb   = wave & 3;        // row block
    const int c    = blockIdx.y;

    const float* embc = emb + (size_t)c * (KCB * VDIM);

    // --- staging: thread tid owns code tid; no cross-lane ops ---
    {
        const int code = tid;
        const float4* ef = (const float4*)embc + code * 16;
        float s = 0.f;
#pragma unroll
        for (int koct = 0; koct < 8; ++koct) {       // 8 floats per k-octet
            const float4 a = ef[koct * 2], b = ef[koct * 2 + 1];
            s = fmaf(a.x, a.x, s); s = fmaf(a.y, a.y, s);
            s = fmaf(a.z, a.z, s); s = fmaf(a.w, a.w, s);
            s = fmaf(b.x, b.x, s); s = fmaf(b.y, b.y, s);
            s = fmaf(b.z, b.z, s); s = fmaf(b.w, b.w, s);
            short8 hv;
            hv[0] = (short)bf16r(a.x); hv[1] = (short)bf16r(a.y);
            hv[2] = (short)bf16r(a.z); hv[3] = (short)bf16r(a.w);
            hv[4] = (short)bf16r(b.x); hv[5] = (short)bf16r(b.y);
            hv[6] = (short)bf16r(b.z); hv[7] = (short)bf16r(b.w);
            *(short8*)&eh[(koct * 512 + (code ^ koct)) * 8] = hv;  // XOR swizzle
        }
        e2s[code] = s;                               // exact fp32
    }
    __syncthreads();

    const int mq0 = m ^ quad, mq1 = m ^ (quad + 4);
    const int kbase = z * 256;
    const size_t base1 = (size_t)NROW * CCH * VDIM;
    const size_t base2 = base1 + (size_t)NROW * CCH;

    for (int rt = 0; rt < 2; ++rt) {                 // 2 row-tiles per block
        const int rbase = blockIdx.x * 128 + rt * 64 + wb * 16;

        // --- A fragments: 16 rows, 2 k-halves, x hi/lo ---
        short8 ah[2], al[2];
        {
            const int row = rbase + m;
            const float4* xr = (const float4*)(x + ((size_t)row * CCH + c) * VDIM);
#pragma unroll
            for (int h = 0; h < 2; ++h) {            // k = h*32 + quad*8 + j
                const float4 f0 = xr[h * 8 + quad * 2];
                const float4 f1 = xr[h * 8 + quad * 2 + 1];
                const float fv[8] = {f0.x, f0.y, f0.z, f0.w, f1.x, f1.y, f1.z, f1.w};
                short8 hh, ll;
#pragma unroll
                for (int j = 0; j < 8; ++j) {
                    float r, d;
                    hh[j] = (short)bf16h(fv[j], &r);
                    ll[j] = (short)bf16h(r, &d);
                }
                ah[h] = hh; al[h] = ll;
            }
        }

        float bd[4]; int bkk[4];
#pragma unroll
        for (int j = 0; j < 4; ++j) { bd[j] = 3.4e38f; bkk[j] = 0; }

#pragma unroll 4
        for (int t = 0; t < 16; ++t) {               // 16 tiles = this z-half
            const int kb = kbase + t * 16;
            const int code = kb + m;
            const short8 bh0 = *(const short8*)&eh[( quad      * 512 + kb + mq0) * 8];
            const short8 bh1 = *(const short8*)&eh[((quad + 4) * 512 + kb + mq1) * 8];
            const float e2v = e2s[code];

            floatx4 acc0 = {0.f,0.f,0.f,0.f}, acc1 = {0.f,0.f,0.f,0.f};
            acc0 = __builtin_amdgcn_mfma_f32_16x16x32_bf16(ah[0], bh0, acc0, 0, 0, 0);
            acc1 = __builtin_amdgcn_mfma_f32_16x16x32_bf16(al[0], bh0, acc1, 0, 0, 0);
            acc0 = __builtin_amdgcn_mfma_f32_16x16x32_bf16(ah[1], bh1, acc0, 0, 0, 0);
            acc1 = __builtin_amdgcn_mfma_f32_16x16x32_bf16(al[1], bh1, acc1, 0, 0, 0);

#pragma unroll
            for (int j = 0; j < 4; ++j) {
                const float d0 = fmaf(-2.0f, acc0[j] + acc1[j], e2v);
                if (d0 < bd[j]) { bd[j] = d0; bkk[j] = code; }  // first-min
            }
        }

        // within-quad (16-lane) argmin; tie -> lower code (first-occurrence)
#pragma unroll
        for (int j = 0; j < 4; ++j) {
            float d = bd[j]; int k = bkk[j];
#pragma unroll
            for (int mask = 1; mask < 16; mask <<= 1) {
                const float od = __shfl_xor(d, mask, 64);
                const int   ok = __shfl_xor(k, mask, 64);
                if (od < d || (od == d && ok < k)) { d = od; k = ok; }
            }
            bd[j] = d; bkk[j] = k;
        }

        __syncthreads();     // prior rt's merge reads of sdm/skm complete
        if (m == 0) {
#pragma unroll
            for (int j = 0; j < 4; ++j) {
                sdm[(z * 4 + wb) * 16 + quad * 4 + j] = bd[j];
                skm[(z * 4 + wb) * 16 + quad * 4 + j] = bkk[j];
            }
        }
        __syncthreads();

        // merge halves + epilogue: z==0 waves handle their 16 rows
        if (z == 0) {
#pragma unroll
            for (int j = 0; j < 4; ++j) {
                const int rl = quad * 4 + j;
                const float d0 = sdm[ wb      * 16 + rl];
                const float d1 = sdm[(4 + wb) * 16 + rl];
                const int   k0 = skm[ wb      * 16 + rl];
                const int   k1 = skm[(4 + wb) * 16 + rl];
                const int code = (d1 < d0) ? k1 : k0;  // z0 first => first-min
                const int row  = rbase + rl;

                const float4 t4 = ((const float4*)(x + ((size_t)row * CCH + c) * VDIM))[m];
                const float4 e4 = ((const float4*)(embc + (size_t)code * VDIM))[m];
                float4 w;
                w.x = (e4.x - t4.x) + t4.x;            // out0 = (output - x) + x
                w.y = (e4.y - t4.y) + t4.y;
                w.z = (e4.z - t4.z) + t4.z;
                w.w = (e4.w - t4.w) + t4.w;
                ((float4*)(out + ((size_t)row * CCH + c) * VDIM))[m] = w;
                float s = 0.f, dx;
                dx = t4.x - e4.x; s = fmaf(dx, dx, s);
                dx = t4.y - e4.y; s = fmaf(dx, dx, s);
                dx = t4.z - e4.z; s = fmaf(dx, dx, s);
                dx = t4.w - e4.w; s = fmaf(dx, dx, s);
                s += __shfl_xor(s, 1, 64);
                s += __shfl_xor(s, 2, 64);
                s += __shfl_xor(s, 4, 64);
                s += __shfl_xor(s, 8, 64);
                if (m == 0) {
                    const size_t idx = (size_t)row * CCH + c;
                    out[base1 + idx] = s;              // out1
                    out[base2 + idx] = s;              // out2 (identical in ref)
                }
            }
        }
    }
}

extern "C" void kernel_launch(void* const* d_in, const int* in_sizes, int n_in,
                              void* d_out, int out_size, void* d_ws, size_t ws_size,
                              hipStream_t stream) {
    const float* x   = (const float*)d_in[0];
    const float* emb = (const float*)d_in[1];
    float* out = (float*)d_out;
    const size_t lds_bytes = 65536u + 2048u + 512u + 512u;   // 68608 B
    vq_fused<<<dim3(NROW / 128, CCH), dim3(512), lds_bytes, stream>>>(x, emb, out);
}